// Round 1
// baseline (42881.219 us; speedup 1.0000x reference)
//
#include <hip/hip_runtime.h>
#include <hip/hip_bf16.h>
#include <hip/hip_cooperative_groups.h>

namespace cg = cooperative_groups;

typedef unsigned short u16;
typedef unsigned int u32;
typedef __attribute__((ext_vector_type(4))) unsigned int u32x4;
typedef __attribute__((ext_vector_type(8))) short bf16x8;
typedef __attribute__((ext_vector_type(4))) float f32x4;

__device__ __forceinline__ u16 f2bf(float f) {
    u32 u = __float_as_uint(f);
    u32 r = (u + 0x7fffu + ((u >> 16) & 1u)) >> 16;
    return (u16)r;
}
__device__ __forceinline__ float bf2f(u16 b) {
    return __uint_as_float(((u32)b) << 16);
}
__device__ __forceinline__ float sigm(float x) {
    return 1.0f / (1.0f + __expf(-x));
}
__device__ __forceinline__ float tanh_fast(float x) {
    return 1.0f - 2.0f / (1.0f + __expf(2.0f * x));
}

// ---------------------------------------------------------------- casts
__global__ void cast_bf16_kernel(const float* __restrict__ in, u16* __restrict__ out, int n) {
    int i = (blockIdx.x * blockDim.x + threadIdx.x) * 4;
    int stride = gridDim.x * blockDim.x * 4;
    for (; i + 3 < n; i += stride) {
        float4 v = *(const float4*)&in[i];
        ushort4 o;
        o.x = f2bf(v.x); o.y = f2bf(v.y); o.z = f2bf(v.z); o.w = f2bf(v.w);
        *(ushort4*)&out[i] = o;
    }
}

// ---------------------------------------------------------------- GEMM (TN)
// A: [M,K] bf16 row-major (K contig); B: [N,K] bf16 row-major.
// mode 1: out bf16 xg, row permuted (m = b*1024+t -> row' = t*32+b), +bias0[n]+bias1[n]
// mode 2: out fp32: n<512 -> keys at m*512+n (+bias0), else values at 2^24 + m*512+(n-512) (+bias1)
#define BM 128
#define BN 128
#define BK 64

__global__ __launch_bounds__(256) void gemm_tn(
    const u16* __restrict__ A, const u16* __restrict__ Bm,
    int M, int N, int K,
    const float* __restrict__ bias0, const float* __restrict__ bias1,
    u16* __restrict__ outB, float* __restrict__ outF, int mode)
{
    __shared__ __align__(16) u16 As[BM][BK];
    __shared__ __align__(16) u16 Bs[BN][BK];
    const int tid = threadIdx.x;
    const int lane = tid & 63;
    const int w = tid >> 6;
    const int wm = w >> 1, wn = w & 1;
    const int m0 = blockIdx.y * BM, n0 = blockIdx.x * BN;

    const u16* Aptr = A + (size_t)m0 * K;
    const u16* Bptr = Bm + (size_t)n0 * K;

    f32x4 acc[4][4];
#pragma unroll
    for (int i = 0; i < 4; i++)
#pragma unroll
        for (int j = 0; j < 4; j++)
            acc[i][j] = (f32x4){0.f, 0.f, 0.f, 0.f};

    u32x4 ra[4], rb[4];
    // issue loads for kb=0
#pragma unroll
    for (int i = 0; i < 4; i++) {
        int cid = i * 256 + tid;
        int r = cid >> 3, s = cid & 7;
        int gc = s ^ (r & 7);
        ra[i] = *(const u32x4*)&Aptr[(size_t)r * K + gc * 8];
        rb[i] = *(const u32x4*)&Bptr[(size_t)r * K + gc * 8];
    }

    for (int kb = 0; kb < K; kb += BK) {
        __syncthreads();   // previous compute done; LDS free
#pragma unroll
        for (int i = 0; i < 4; i++) {
            int cid = i * 256 + tid;
            int r = cid >> 3, s = cid & 7;
            *(u32x4*)&As[r][s * 8] = ra[i];
            *(u32x4*)&Bs[r][s * 8] = rb[i];
        }
        __syncthreads();
        if (kb + BK < K) {
            int kn = kb + BK;
#pragma unroll
            for (int i = 0; i < 4; i++) {
                int cid = i * 256 + tid;
                int r = cid >> 3, s = cid & 7;
                int gc = s ^ (r & 7);
                ra[i] = *(const u32x4*)&Aptr[(size_t)r * K + kn + gc * 8];
                rb[i] = *(const u32x4*)&Bptr[(size_t)r * K + kn + gc * 8];
            }
        }
        // compute on staged BK=64 (two MFMA k-steps)
#pragma unroll
        for (int kk = 0; kk < 2; kk++) {
            bf16x8 af[4], bfr[4];
#pragma unroll
            for (int mi = 0; mi < 4; mi++) {
                int rr = wm * 64 + mi * 16 + (lane & 15);
                int q = kk * 4 + (lane >> 4);
                af[mi] = *(const bf16x8*)&As[rr][(q ^ (rr & 7)) * 8];
            }
#pragma unroll
            for (int ni = 0; ni < 4; ni++) {
                int rr = wn * 64 + ni * 16 + (lane & 15);
                int q = kk * 4 + (lane >> 4);
                bfr[ni] = *(const bf16x8*)&Bs[rr][(q ^ (rr & 7)) * 8];
            }
#pragma unroll
            for (int mi = 0; mi < 4; mi++)
#pragma unroll
                for (int ni = 0; ni < 4; ni++)
                    acc[mi][ni] = __builtin_amdgcn_mfma_f32_16x16x32_bf16(
                        af[mi], bfr[ni], acc[mi][ni], 0, 0, 0);
        }
    }

    // epilogue
#pragma unroll
    for (int mi = 0; mi < 4; mi++) {
#pragma unroll
        for (int ni = 0; ni < 4; ni++) {
            int n = n0 + wn * 64 + ni * 16 + (lane & 15);
#pragma unroll
            for (int v = 0; v < 4; v++) {
                int m = m0 + wm * 64 + mi * 16 + (lane >> 4) * 4 + v;
                float val = acc[mi][ni][v];
                if (mode == 1) {
                    val += bias0[n] + bias1[n];
                    int t = m & 1023, b = m >> 10;
                    outB[(size_t)(t * 32 + b) * 4096 + n] = f2bf(val);
                } else {
                    if (n < 512) {
                        outF[(size_t)m * 512 + n] = val + bias0[n];
                    } else {
                        outF[16777216u + (size_t)m * 512 + (n - 512)] = val + bias1[n - 512];
                    }
                }
            }
        }
    }
}

// ---------------------------------------------------------------- recurrence
// grid = 128 blocks x 256 thr (cooperative). Block g owns hidden units [8g, 8g+8).
// W_hh slice (32 rows x 1024) lives in registers (bf16x8 breg[32] per lane).
// h_{t-1} broadcast via hs global buffer -> LDS (swizzled). c in registers.
__global__ __launch_bounds__(256, 1) void lstm_rec(
    const u16* __restrict__ Whh,   // [4096][1024] bf16
    const u16* __restrict__ xg,    // [(t*32+b)][4096] bf16 (biases folded in)
    u16* __restrict__ hs)          // [(b*1024+t)][1024] bf16
{
    __shared__ __align__(16) u16 hl[32][1024];   // 64 KB, chunk-swizzled
    float* gbuf = (float*)&hl[0][0];             // aliased [32][36] fp32 gate buffer

    const int tid = threadIdx.x;
    const int lane = tid & 63;
    const int w = tid >> 6;
    const int mw = w >> 1, nw = w & 1;
    const int u0 = blockIdx.x * 8;

    // preload W_hh fragments: wave tile nw covers gate rows n = nw*16 + (lane&15)
    bf16x8 breg[32];
    {
        int n = nw * 16 + (lane & 15);
        int gr = (n >> 3) * 1024 + u0 + (n & 7);   // gate-major global row
        const u16* wp = Whh + (size_t)gr * 1024 + (lane >> 4) * 8;
#pragma unroll
        for (int kk = 0; kk < 32; kk++)
            breg[kk] = *(const bf16x8*)&wp[kk * 32];
    }

    const int ab = tid >> 3, au = tid & 7;   // activation thread -> (batch, unit)
    float c = 0.f;
    u16 xi, xf, xgr, xo;
    {
        const u16* xp = xg + (size_t)ab * 4096 + u0 + au;   // t = 0
        xi = xp[0]; xf = xp[1024]; xgr = xp[2048]; xo = xp[3072];
    }

    cg::grid_group grid = cg::this_grid();

    for (int t = 0; t < 1024; t++) {
        float gi, gf, gg, go;
        if (t == 0) {
            gi = bf2f(xi); gf = bf2f(xf); gg = bf2f(xgr); go = bf2f(xo);
        } else {
            // stage h_{t-1}: 32 rows x 1024 bf16, coalesced, swizzled into LDS
#pragma unroll
            for (int i = 0; i < 16; i++) {
                int cid = i * 256 + tid;         // 4096 16B chunks
                int b = cid >> 7, cc = cid & 127;
                u32x4 v = *(const u32x4*)&hs[((size_t)(b << 10) + (t - 1)) * 1024 + cc * 8];
                *(u32x4*)&hl[b][(cc ^ (b & 7)) * 8] = v;
            }
            __syncthreads();
            // GEMM: D[batch][gate-row], wave tile (mw, nw), K=1024
            f32x4 ae = {0.f, 0.f, 0.f, 0.f}, ao = {0.f, 0.f, 0.f, 0.f};
            {
                int row = mw * 16 + (lane & 15);
                int qb = (lane >> 4);
#pragma unroll
                for (int kk = 0; kk < 32; kk += 2) {
                    int q0 = kk * 4 + qb;
                    int q1 = (kk + 1) * 4 + qb;
                    bf16x8 a0 = *(const bf16x8*)&hl[row][(q0 ^ (row & 7)) * 8];
                    bf16x8 a1 = *(const bf16x8*)&hl[row][(q1 ^ (row & 7)) * 8];
                    ae = __builtin_amdgcn_mfma_f32_16x16x32_bf16(a0, breg[kk], ae, 0, 0, 0);
                    ao = __builtin_amdgcn_mfma_f32_16x16x32_bf16(a1, breg[kk + 1], ao, 0, 0, 0);
                }
            }
            __syncthreads();   // all hl reads done before aliasing as gbuf
            {
                int n = nw * 16 + (lane & 15);
#pragma unroll
                for (int v = 0; v < 4; v++) {
                    int m = mw * 16 + (lane >> 4) * 4 + v;
                    gbuf[m * 36 + n] = ae[v] + ao[v];
                }
            }
            __syncthreads();
            gi = gbuf[ab * 36 + au]       + bf2f(xi);
            gf = gbuf[ab * 36 + 8 + au]   + bf2f(xf);
            gg = gbuf[ab * 36 + 16 + au]  + bf2f(xgr);
            go = gbuf[ab * 36 + 24 + au]  + bf2f(xo);
        }
        // prefetch next step's xg (hides HBM latency behind sync+gemm)
        if (t < 1023) {
            const u16* xp = xg + ((size_t)(t + 1) * 32 + ab) * 4096 + u0 + au;
            xi = xp[0]; xf = xp[1024]; xgr = xp[2048]; xo = xp[3072];
        }
        // activation + state update (PyTorch gate order i,f,g,o)
        float iv = sigm(gi);
        float fv = sigm(gf);
        float gv = tanh_fast(gg);
        float ov = sigm(go);
        c = fv * c + iv * gv;
        float h = ov * tanh_fast(c);
        hs[((size_t)(ab << 10) + t) * 1024 + u0 + au] = f2bf(h);
        __threadfence();          // release hs stores device-wide
        if (t < 1023) {
            grid.sync();
            __threadfence();      // acquire side
        }
    }
}

// ---------------------------------------------------------------- launch
extern "C" void kernel_launch(void* const* d_in, const int* in_sizes, int n_in,
                              void* d_out, int out_size, void* d_ws, size_t ws_size,
                              hipStream_t stream) {
    const float* x     = (const float*)d_in[0];
    const float* W_ih  = (const float*)d_in[1];
    const float* W_hh  = (const float*)d_in[2];
    const float* b_ih  = (const float*)d_in[3];
    const float* b_hh  = (const float*)d_in[4];
    const float* W_key = (const float*)d_in[5];
    const float* b_key = (const float*)d_in[6];
    const float* W_val = (const float*)d_in[7];
    const float* b_val = (const float*)d_in[8];
    float* out = (float*)d_out;

    char* ws = (char*)d_ws;
    u16* xg  = (u16*)(ws);                        // 256 MB  [S*32][4096]
    u16* hs  = (u16*)(ws + 268435456ull);         //  64 MB  [32*1024][1024]
    u16* xb  = (u16*)(ws + 335544320ull);         //  32 MB  x bf16
    u16* whh = (u16*)(ws + 369098752ull);         //   8 MB
    u16* wih = (u16*)(ws + 377487360ull);         //   4 MB
    u16* wkv = (u16*)(ws + 381681664ull);         //   2 MB  [Wkey;Wval]
    // total ws needed: ~366 MB

    cast_bf16_kernel<<<1024, 256, 0, stream>>>(x, xb, 32 * 1024 * 512);
    cast_bf16_kernel<<<256, 256, 0, stream>>>(W_ih, wih, 4096 * 512);
    cast_bf16_kernel<<<256, 256, 0, stream>>>(W_hh, whh, 4096 * 1024);
    cast_bf16_kernel<<<64, 256, 0, stream>>>(W_key, wkv, 512 * 1024);
    cast_bf16_kernel<<<64, 256, 0, stream>>>(W_val, wkv + 512 * 1024, 512 * 1024);

    // phase 1: xg = x @ W_ih^T + b_ih + b_hh  (row-permuted bf16)
    gemm_tn<<<dim3(4096 / BN, 32768 / BM), 256, 0, stream>>>(
        xb, wih, 32768, 4096, 512, b_ih, b_hh, xg, nullptr, 1);

    // phase 2: recurrence (cooperative, 128 WGs)
    {
        void* args[] = { (void*)&whh, (void*)&xg, (void*)&hs };
        hipLaunchCooperativeKernel((void*)lstm_rec, dim3(128), dim3(256), args, 0, stream);
    }

    // phase 3: keys/values = hs @ [Wkey;Wval]^T + bias
    gemm_tn<<<dim3(1024 / BN, 32768 / BM), 256, 0, stream>>>(
        hs, wkv, 32768, 1024, 1024, b_key, b_val, nullptr, out, 2);
}

// Round 2
// 12455.684 us; speedup vs baseline: 3.4427x; 3.4427x over previous
//
#include <hip/hip_runtime.h>
#include <hip/hip_bf16.h>

typedef unsigned short u16;
typedef unsigned int u32;
typedef __attribute__((ext_vector_type(4))) unsigned int u32x4;
typedef __attribute__((ext_vector_type(8))) short bf16x8;
typedef __attribute__((ext_vector_type(4))) float f32x4;

__device__ __forceinline__ u16 f2bf(float f) {
    u32 u = __float_as_uint(f);
    u32 r = (u + 0x7fffu + ((u >> 16) & 1u)) >> 16;
    return (u16)r;
}
__device__ __forceinline__ float bf2f(u16 b) {
    return __uint_as_float(((u32)b) << 16);
}
__device__ __forceinline__ float sigm(float x) {
    return 1.0f / (1.0f + __expf(-x));
}
__device__ __forceinline__ float tanh_fast(float x) {
    return 1.0f - 2.0f / (1.0f + __expf(2.0f * x));
}

// ---------------------------------------------------------------- casts
__global__ void cast_bf16_kernel(const float* __restrict__ in, u16* __restrict__ out, int n) {
    int i = (blockIdx.x * blockDim.x + threadIdx.x) * 4;
    int stride = gridDim.x * blockDim.x * 4;
    for (; i + 3 < n; i += stride) {
        float4 v = *(const float4*)&in[i];
        ushort4 o;
        o.x = f2bf(v.x); o.y = f2bf(v.y); o.z = f2bf(v.z); o.w = f2bf(v.w);
        *(ushort4*)&out[i] = o;
    }
}

__global__ void init_counter_kernel(u32* c) {
    if (threadIdx.x == 0 && blockIdx.x == 0) *c = 0u;
}

// ---------------------------------------------------------------- GEMM (TN)
// A: [M,K] bf16 row-major (K contig); B: [N,K] bf16 row-major.
// mode 1: out bf16 xg, row permuted (m = b*1024+t -> row' = t*32+b), +bias0[n]+bias1[n]
// mode 2: out fp32: n<512 -> keys at m*512+n (+bias0), else values at 2^24 + m*512+(n-512) (+bias1)
#define BM 128
#define BN 128
#define BK 64

__global__ __launch_bounds__(256) void gemm_tn(
    const u16* __restrict__ A, const u16* __restrict__ Bm,
    int M, int N, int K,
    const float* __restrict__ bias0, const float* __restrict__ bias1,
    u16* __restrict__ outB, float* __restrict__ outF, int mode)
{
    __shared__ __align__(16) u16 As[BM][BK];
    __shared__ __align__(16) u16 Bs[BN][BK];
    const int tid = threadIdx.x;
    const int lane = tid & 63;
    const int w = tid >> 6;
    const int wm = w >> 1, wn = w & 1;
    const int m0 = blockIdx.y * BM, n0 = blockIdx.x * BN;

    const u16* Aptr = A + (size_t)m0 * K;
    const u16* Bptr = Bm + (size_t)n0 * K;

    f32x4 acc[4][4];
#pragma unroll
    for (int i = 0; i < 4; i++)
#pragma unroll
        for (int j = 0; j < 4; j++)
            acc[i][j] = (f32x4){0.f, 0.f, 0.f, 0.f};

    u32x4 ra[4], rb[4];
#pragma unroll
    for (int i = 0; i < 4; i++) {
        int cid = i * 256 + tid;
        int r = cid >> 3, s = cid & 7;
        int gc = s ^ (r & 7);
        ra[i] = *(const u32x4*)&Aptr[(size_t)r * K + gc * 8];
        rb[i] = *(const u32x4*)&Bptr[(size_t)r * K + gc * 8];
    }

    for (int kb = 0; kb < K; kb += BK) {
        __syncthreads();
#pragma unroll
        for (int i = 0; i < 4; i++) {
            int cid = i * 256 + tid;
            int r = cid >> 3, s = cid & 7;
            *(u32x4*)&As[r][s * 8] = ra[i];
            *(u32x4*)&Bs[r][s * 8] = rb[i];
        }
        __syncthreads();
        if (kb + BK < K) {
            int kn = kb + BK;
#pragma unroll
            for (int i = 0; i < 4; i++) {
                int cid = i * 256 + tid;
                int r = cid >> 3, s = cid & 7;
                int gc = s ^ (r & 7);
                ra[i] = *(const u32x4*)&Aptr[(size_t)r * K + kn + gc * 8];
                rb[i] = *(const u32x4*)&Bptr[(size_t)r * K + kn + gc * 8];
            }
        }
#pragma unroll
        for (int kk = 0; kk < 2; kk++) {
            bf16x8 af[4], bfr[4];
#pragma unroll
            for (int mi = 0; mi < 4; mi++) {
                int rr = wm * 64 + mi * 16 + (lane & 15);
                int q = kk * 4 + (lane >> 4);
                af[mi] = *(const bf16x8*)&As[rr][(q ^ (rr & 7)) * 8];
            }
#pragma unroll
            for (int ni = 0; ni < 4; ni++) {
                int rr = wn * 64 + ni * 16 + (lane & 15);
                int q = kk * 4 + (lane >> 4);
                bfr[ni] = *(const bf16x8*)&Bs[rr][(q ^ (rr & 7)) * 8];
            }
#pragma unroll
            for (int mi = 0; mi < 4; mi++)
#pragma unroll
                for (int ni = 0; ni < 4; ni++)
                    acc[mi][ni] = __builtin_amdgcn_mfma_f32_16x16x32_bf16(
                        af[mi], bfr[ni], acc[mi][ni], 0, 0, 0);
        }
    }

#pragma unroll
    for (int mi = 0; mi < 4; mi++) {
#pragma unroll
        for (int ni = 0; ni < 4; ni++) {
            int n = n0 + wn * 64 + ni * 16 + (lane & 15);
#pragma unroll
            for (int v = 0; v < 4; v++) {
                int m = m0 + wm * 64 + mi * 16 + (lane >> 4) * 4 + v;
                float val = acc[mi][ni][v];
                if (mode == 1) {
                    val += bias0[n] + bias1[n];
                    int t = m & 1023, b = m >> 10;
                    outB[(size_t)(t * 32 + b) * 4096 + n] = f2bf(val);
                } else {
                    if (n < 512) {
                        outF[(size_t)m * 512 + n] = val + bias0[n];
                    } else {
                        outF[16777216u + (size_t)m * 512 + (n - 512)] = val + bias1[n - 512];
                    }
                }
            }
        }
    }
}

// ---------------------------------------------------------------- recurrence
// 128 blocks x 256 thr (cooperative launch only for co-residency; no grid.sync).
// Block g owns hidden units [8g, 8g+8). W_hh slice in registers.
// h broadcast via hs + lightweight monotonic-counter barrier:
//   - h published as agent-scope relaxed atomic dword stores (write-through L2)
//   - arrive: one relaxed agent atomicAdd per block after __syncthreads
//   - wait: tid0 spins on relaxed agent atomic load; acquire fence; __syncthreads
__global__ __launch_bounds__(256, 1) void lstm_rec(
    const u16* __restrict__ Whh,   // [4096][1024] bf16
    const u16* __restrict__ xg,    // [(t*32+b)][4096] bf16 (biases folded in)
    u16* __restrict__ hs,          // [(b*1024+t)][1024] bf16
    u32* __restrict__ cnt)         // barrier counter (init 0)
{
    __shared__ __align__(16) u16 hl[32][1024];   // 64 KB, chunk-swizzled
    float* gbuf = (float*)&hl[0][0];             // aliased [32][36] fp32 gate buffer

    const int tid = threadIdx.x;
    const int lane = tid & 63;
    const int w = tid >> 6;
    const int mw = w >> 1, nw = w & 1;
    const int u0 = blockIdx.x * 8;

    // preload W_hh fragments: wave tile nw covers gate rows n = nw*16 + (lane&15)
    bf16x8 breg[32];
    {
        int n = nw * 16 + (lane & 15);
        int gr = (n >> 3) * 1024 + u0 + (n & 7);   // gate-major global row
        const u16* wp = Whh + (size_t)gr * 1024 + (lane >> 4) * 8;
#pragma unroll
        for (int kk = 0; kk < 32; kk++)
            breg[kk] = *(const bf16x8*)&wp[kk * 32];
    }

    const int ab = tid >> 3, au = tid & 7;   // activation thread -> (batch, unit)
    float c = 0.f;
    u16 xi, xf, xgr, xo;
    {
        const u16* xp = xg + (size_t)ab * 4096 + u0 + au;   // t = 0
        xi = xp[0]; xf = xp[1024]; xgr = xp[2048]; xo = xp[3072];
    }

    for (int t = 0; t < 1024; t++) {
        float gi, gf, gg, go;
        if (t == 0) {
            gi = bf2f(xi); gf = bf2f(xf); gg = bf2f(xgr); go = bf2f(xo);
        } else {
            // wait until all 128 blocks published h(t-1)
            if (tid == 0) {
                while (__hip_atomic_load(cnt, __ATOMIC_RELAXED, __HIP_MEMORY_SCOPE_AGENT)
                       < 128u * (u32)t) { }
            }
            __syncthreads();
            __builtin_amdgcn_fence(__ATOMIC_ACQUIRE, "agent");  // per-wave L2 inv (cheap; lines clean)

            // stage h_{t-1}: 32 rows x 1024 bf16, coalesced, swizzled into LDS
#pragma unroll
            for (int i = 0; i < 16; i++) {
                int cid = i * 256 + tid;         // 4096 16B chunks
                int b = cid >> 7, cc = cid & 127;
                u32x4 v = *(const u32x4*)&hs[((size_t)(b << 10) + (t - 1)) * 1024 + cc * 8];
                *(u32x4*)&hl[b][(cc ^ (b & 7)) * 8] = v;
            }
            __syncthreads();
            // GEMM: D[batch][gate-row], wave tile (mw, nw), K=1024
            f32x4 ae = {0.f, 0.f, 0.f, 0.f}, ao = {0.f, 0.f, 0.f, 0.f};
            {
                int row = mw * 16 + (lane & 15);
                int qb = (lane >> 4);
#pragma unroll
                for (int kk = 0; kk < 32; kk += 2) {
                    int q0 = kk * 4 + qb;
                    int q1 = (kk + 1) * 4 + qb;
                    bf16x8 a0 = *(const bf16x8*)&hl[row][(q0 ^ (row & 7)) * 8];
                    bf16x8 a1 = *(const bf16x8*)&hl[row][(q1 ^ (row & 7)) * 8];
                    ae = __builtin_amdgcn_mfma_f32_16x16x32_bf16(a0, breg[kk], ae, 0, 0, 0);
                    ao = __builtin_amdgcn_mfma_f32_16x16x32_bf16(a1, breg[kk + 1], ao, 0, 0, 0);
                }
            }
            __syncthreads();   // all hl reads done before aliasing as gbuf
            {
                int n = nw * 16 + (lane & 15);
#pragma unroll
                for (int v = 0; v < 4; v++) {
                    int m = mw * 16 + (lane >> 4) * 4 + v;
                    gbuf[m * 36 + n] = ae[v] + ao[v];
                }
            }
            __syncthreads();
            gi = gbuf[ab * 36 + au]       + bf2f(xi);
            gf = gbuf[ab * 36 + 8 + au]   + bf2f(xf);
            gg = gbuf[ab * 36 + 16 + au]  + bf2f(xgr);
            go = gbuf[ab * 36 + 24 + au]  + bf2f(xo);
        }
        // prefetch next step's xg (hides HBM latency behind barrier+gemm)
        if (t < 1023) {
            const u16* xp = xg + ((size_t)(t + 1) * 32 + ab) * 4096 + u0 + au;
            xi = xp[0]; xf = xp[1024]; xgr = xp[2048]; xo = xp[3072];
        }
        // activation + state update (PyTorch gate order i,f,g,o)
        float iv = sigm(gi);
        float fv = sigm(gf);
        float gv = tanh_fast(gg);
        float ov = sigm(go);
        c = fv * c + iv * gv;
        float h = ov * tanh_fast(c);

        // publish h: pack 2 units/dword, agent-scope atomic store (write-through L2)
        {
            u32 mine = (u32)f2bf(h);
            u32 other = (u32)__shfl_xor((int)mine, 1, 64);
            if ((au & 1) == 0) {
                u32 packed = mine | (other << 16);
                u32* p = (u32*)&hs[((size_t)(ab << 10) + t) * 1024 + u0 + au];
                __hip_atomic_store(p, packed, __ATOMIC_RELAXED, __HIP_MEMORY_SCOPE_AGENT);
            }
        }
        __syncthreads();   // each wave drains vmcnt before barrier -> stores at coherent point
        if (t < 1023 && tid == 0) {
            __hip_atomic_fetch_add(cnt, 1u, __ATOMIC_RELAXED, __HIP_MEMORY_SCOPE_AGENT);
        }
    }
}

// ---------------------------------------------------------------- launch
extern "C" void kernel_launch(void* const* d_in, const int* in_sizes, int n_in,
                              void* d_out, int out_size, void* d_ws, size_t ws_size,
                              hipStream_t stream) {
    const float* x     = (const float*)d_in[0];
    const float* W_ih  = (const float*)d_in[1];
    const float* W_hh  = (const float*)d_in[2];
    const float* b_ih  = (const float*)d_in[3];
    const float* b_hh  = (const float*)d_in[4];
    const float* W_key = (const float*)d_in[5];
    const float* b_key = (const float*)d_in[6];
    const float* W_val = (const float*)d_in[7];
    const float* b_val = (const float*)d_in[8];
    float* out = (float*)d_out;

    char* ws = (char*)d_ws;
    u16* xg  = (u16*)(ws);                        // 256 MB  [S*32][4096]
    u16* hs  = (u16*)(ws + 268435456ull);         //  64 MB  [32*1024][1024]
    u16* xb  = (u16*)(ws + 335544320ull);         //  32 MB  x bf16
    u16* whh = (u16*)(ws + 369098752ull);         //   8 MB
    u16* wih = (u16*)(ws + 377487360ull);         //   4 MB
    u16* wkv = (u16*)(ws + 381681664ull);         //   2 MB  [Wkey;Wval]
    u32* cnt = (u32*)(ws + 383778816ull);         //   4 B   barrier counter

    cast_bf16_kernel<<<1024, 256, 0, stream>>>(x, xb, 32 * 1024 * 512);
    cast_bf16_kernel<<<256, 256, 0, stream>>>(W_ih, wih, 4096 * 512);
    cast_bf16_kernel<<<256, 256, 0, stream>>>(W_hh, whh, 4096 * 1024);
    cast_bf16_kernel<<<64, 256, 0, stream>>>(W_key, wkv, 512 * 1024);
    cast_bf16_kernel<<<64, 256, 0, stream>>>(W_val, wkv + 512 * 1024, 512 * 1024);
    init_counter_kernel<<<1, 64, 0, stream>>>(cnt);

    // phase 1: xg = x @ W_ih^T + b_ih + b_hh  (row-permuted bf16)
    gemm_tn<<<dim3(4096 / BN, 32768 / BM), 256, 0, stream>>>(
        xb, wih, 32768, 4096, 512, b_ih, b_hh, xg, nullptr, 1);

    // phase 2: recurrence (cooperative launch for co-residency guarantee)
    {
        void* args[] = { (void*)&whh, (void*)&xg, (void*)&hs, (void*)&cnt };
        hipLaunchCooperativeKernel((void*)lstm_rec, dim3(128), dim3(256), args, 0, stream);
    }

    // phase 3: keys/values = hs @ [Wkey;Wval]^T + bias
    gemm_tn<<<dim3(1024 / BN, 32768 / BM), 256, 0, stream>>>(
        hs, wkv, 32768, 1024, 1024, b_key, b_val, nullptr, out, 2);
}

// Round 3
// 11795.608 us; speedup vs baseline: 3.6354x; 1.0560x over previous
//
#include <hip/hip_runtime.h>
#include <hip/hip_bf16.h>

typedef unsigned short u16;
typedef unsigned int u32;
typedef __attribute__((ext_vector_type(4))) unsigned int u32x4;
typedef __attribute__((ext_vector_type(8))) short bf16x8;
typedef __attribute__((ext_vector_type(4))) float f32x4;

__device__ __forceinline__ u16 f2bf(float f) {
    u32 u = __float_as_uint(f);
    u32 r = (u + 0x7fffu + ((u >> 16) & 1u)) >> 16;
    return (u16)r;
}
__device__ __forceinline__ float bf2f(u16 b) {
    return __uint_as_float(((u32)b) << 16);
}
__device__ __forceinline__ float sigm(float x) {
    return 1.0f / (1.0f + __expf(-x));
}
__device__ __forceinline__ float tanh_fast(float x) {
    return 1.0f - 2.0f / (1.0f + __expf(2.0f * x));
}

// ---------------------------------------------------------------- casts
__global__ void cast_bf16_kernel(const float* __restrict__ in, u16* __restrict__ out, int n) {
    int i = (blockIdx.x * blockDim.x + threadIdx.x) * 4;
    int stride = gridDim.x * blockDim.x * 4;
    for (; i + 3 < n; i += stride) {
        float4 v = *(const float4*)&in[i];
        ushort4 o;
        o.x = f2bf(v.x); o.y = f2bf(v.y); o.z = f2bf(v.z); o.w = f2bf(v.w);
        *(ushort4*)&out[i] = o;
    }
}

// zero the 8 KB flag region (harness poisons ws with 0xAA every launch!)
__global__ void init_flags_kernel(u32* f) {
    f[blockIdx.x * 256 + threadIdx.x] = 0u;
}

// ---------------------------------------------------------------- GEMM (TN)
// A: [M,K] bf16 row-major; B: [N,K] bf16 row-major.
// mode 1: out bf16 xg, row permuted (m=b*1024+t -> t*32+b), COLUMN permuted
//         unit-major: col = (n&1023)*4 + (n>>10); +bias0[n]+bias1[n]
// mode 2: out fp32 keys/values split (+bias)
#define BM 128
#define BN 128
#define BK 64

__global__ __launch_bounds__(256) void gemm_tn(
    const u16* __restrict__ A, const u16* __restrict__ Bm,
    int M, int N, int K,
    const float* __restrict__ bias0, const float* __restrict__ bias1,
    u16* __restrict__ outB, float* __restrict__ outF, int mode)
{
    __shared__ __align__(16) u16 As[BM][BK];
    __shared__ __align__(16) u16 Bs[BN][BK];
    const int tid = threadIdx.x;
    const int lane = tid & 63;
    const int w = tid >> 6;
    const int wm = w >> 1, wn = w & 1;
    const int m0 = blockIdx.y * BM, n0 = blockIdx.x * BN;

    const u16* Aptr = A + (size_t)m0 * K;
    const u16* Bptr = Bm + (size_t)n0 * K;

    f32x4 acc[4][4];
#pragma unroll
    for (int i = 0; i < 4; i++)
#pragma unroll
        for (int j = 0; j < 4; j++)
            acc[i][j] = (f32x4){0.f, 0.f, 0.f, 0.f};

    u32x4 ra[4], rb[4];
#pragma unroll
    for (int i = 0; i < 4; i++) {
        int cid = i * 256 + tid;
        int r = cid >> 3, s = cid & 7;
        int gc = s ^ (r & 7);
        ra[i] = *(const u32x4*)&Aptr[(size_t)r * K + gc * 8];
        rb[i] = *(const u32x4*)&Bptr[(size_t)r * K + gc * 8];
    }

    for (int kb = 0; kb < K; kb += BK) {
        __syncthreads();
#pragma unroll
        for (int i = 0; i < 4; i++) {
            int cid = i * 256 + tid;
            int r = cid >> 3, s = cid & 7;
            *(u32x4*)&As[r][s * 8] = ra[i];
            *(u32x4*)&Bs[r][s * 8] = rb[i];
        }
        __syncthreads();
        if (kb + BK < K) {
            int kn = kb + BK;
#pragma unroll
            for (int i = 0; i < 4; i++) {
                int cid = i * 256 + tid;
                int r = cid >> 3, s = cid & 7;
                int gc = s ^ (r & 7);
                ra[i] = *(const u32x4*)&Aptr[(size_t)r * K + kn + gc * 8];
                rb[i] = *(const u32x4*)&Bptr[(size_t)r * K + kn + gc * 8];
            }
        }
#pragma unroll
        for (int kk = 0; kk < 2; kk++) {
            bf16x8 af[4], bfr[4];
#pragma unroll
            for (int mi = 0; mi < 4; mi++) {
                int rr = wm * 64 + mi * 16 + (lane & 15);
                int q = kk * 4 + (lane >> 4);
                af[mi] = *(const bf16x8*)&As[rr][(q ^ (rr & 7)) * 8];
            }
#pragma unroll
            for (int ni = 0; ni < 4; ni++) {
                int rr = wn * 64 + ni * 16 + (lane & 15);
                int q = kk * 4 + (lane >> 4);
                bfr[ni] = *(const bf16x8*)&Bs[rr][(q ^ (rr & 7)) * 8];
            }
#pragma unroll
            for (int mi = 0; mi < 4; mi++)
#pragma unroll
                for (int ni = 0; ni < 4; ni++)
                    acc[mi][ni] = __builtin_amdgcn_mfma_f32_16x16x32_bf16(
                        af[mi], bfr[ni], acc[mi][ni], 0, 0, 0);
        }
    }

#pragma unroll
    for (int mi = 0; mi < 4; mi++) {
#pragma unroll
        for (int ni = 0; ni < 4; ni++) {
            int n = n0 + wn * 64 + ni * 16 + (lane & 15);
#pragma unroll
            for (int v = 0; v < 4; v++) {
                int m = m0 + wm * 64 + mi * 16 + (lane >> 4) * 4 + v;
                float val = acc[mi][ni][v];
                if (mode == 1) {
                    val += bias0[n] + bias1[n];
                    int tt = m & 1023, b = m >> 10;
                    int col = ((n & 1023) << 2) | (n >> 10);   // unit-major, gate-minor
                    outB[(size_t)(tt * 32 + b) * 4096 + col] = f2bf(val);
                } else {
                    if (n < 512) {
                        outF[(size_t)m * 512 + n] = val + bias0[n];
                    } else {
                        outF[16777216u + (size_t)m * 512 + (n - 512)] = val + bias1[n - 512];
                    }
                }
            }
        }
    }
}

// ---------------------------------------------------------------- recurrence
// 128 blocks x 256 thr. Block bid owns hidden units [u0, u0+8),
// u0 = ((bid&7)*16 + (bid>>3))*8  -> XCD x (bid%8) owns contiguous [128x,128x+128).
// Barrier: per-block flag word (own cacheline), relaxed agent store/load.
// Gates exit MFMA, get 4x4 lane-transposed via shfl_xor -> each lane owns
// (batch m, unit u) with all 4 gates in registers; c and h stay in-lane.
__global__ __launch_bounds__(256, 1) void lstm_rec(
    const u16* __restrict__ Whh,   // [4096][1024] bf16 (gate-row major, original)
    const u16* __restrict__ xg,    // [(t*32+b)][4096] bf16, col = unit*4+gate
    u16* __restrict__ hs,          // [(b*1024+t)][1024] bf16
    u32* __restrict__ flags)       // 128 flags at stride 16 dwords, init 0
{
    __shared__ __align__(16) u16 hl[32][1024];   // 64 KB staged h, chunk-swizzled

    const int tid = threadIdx.x;
    const int lane = tid & 63;
    const int w = tid >> 6;
    const int mw = w >> 1, nw = w & 1;
    const int bid = blockIdx.x;
    const int u0 = (((bid & 7) << 4) | (bid >> 3)) << 3;

    // B-frag preload: output col n_local = u*4 + g  (u = n>>2 in [0,4), g = n&3)
    bf16x8 breg[32];
    {
        int nl = lane & 15;
        int gr = (nl & 3) * 1024 + u0 + nw * 4 + (nl >> 2);   // global gate row
        const u16* wp = Whh + (size_t)gr * 1024 + (lane >> 4) * 8;
#pragma unroll
        for (int kk = 0; kk < 32; kk++)
            breg[kk] = *(const bf16x8*)&wp[kk * 32];
    }

    // post-transpose lane identity
    const int m_lane = mw * 16 + ((lane >> 4) << 2) + (lane & 3);   // batch 0..31
    const int u_lane = nw * 4 + ((lane & 15) >> 2);                 // unit 0..7 (local)
    const u16* xg_lane = xg + (size_t)m_lane * 4096 + (u0 + u_lane) * 4;

    float c = 0.f;
    ushort4 xq = *(const ushort4*)xg_lane;   // t = 0 (i,f,g,o contiguous)

    for (int t = 0; t < 1024; t++) {
        float gi, gf, gg, go;
        if (t == 0) {
            gi = bf2f(xq.x); gf = bf2f(xq.y); gg = bf2f(xq.z); go = bf2f(xq.w);
        } else {
            // ---- wait for all 128 blocks to have published h(t-1)
            if (w == 0) {
                const u32* f0 = flags + (lane * 2) * 16;
                const u32* f1 = flags + (lane * 2 + 1) * 16;
                u32 tgt = (u32)t;
                for (;;) {
                    u32 a = __hip_atomic_load(f0, __ATOMIC_RELAXED, __HIP_MEMORY_SCOPE_AGENT);
                    u32 b = __hip_atomic_load(f1, __ATOMIC_RELAXED, __HIP_MEMORY_SCOPE_AGENT);
                    if (__all(a >= tgt && b >= tgt)) break;
                }
            }
            __syncthreads();
            __builtin_amdgcn_fence(__ATOMIC_ACQUIRE, "agent");  // inv stale hs lines

            // ---- stage h(t-1): 64 KB coalesced, swizzled
#pragma unroll
            for (int i = 0; i < 16; i++) {
                int cid = i * 256 + tid;
                int bb = cid >> 7, cc = cid & 127;
                u32x4 v = *(const u32x4*)&hs[((size_t)(bb << 10) + (t - 1)) * 1024 + cc * 8];
                *(u32x4*)&hl[bb][(cc ^ (bb & 7)) * 8] = v;
            }
            __syncthreads();

            // ---- GEMM: D[batch][u*4+g], wave (mw,nw), K=1024
            f32x4 ae = {0.f, 0.f, 0.f, 0.f}, ao = {0.f, 0.f, 0.f, 0.f};
            {
                int row = mw * 16 + (lane & 15);
                int qb = (lane >> 4);
#pragma unroll
                for (int kk = 0; kk < 32; kk += 2) {
                    int q0 = kk * 4 + qb;
                    int q1 = (kk + 1) * 4 + qb;
                    bf16x8 a0 = *(const bf16x8*)&hl[row][(q0 ^ (row & 7)) * 8];
                    bf16x8 a1 = *(const bf16x8*)&hl[row][(q1 ^ (row & 7)) * 8];
                    ae = __builtin_amdgcn_mfma_f32_16x16x32_bf16(a0, breg[kk], ae, 0, 0, 0);
                    ao = __builtin_amdgcn_mfma_f32_16x16x32_bf16(a1, breg[kk + 1], ao, 0, 0, 0);
                }
            }

            // ---- 4x4 lane-register transpose within consecutive 4-lane groups:
            // before: lane&3 = gate, reg = batch-sub; after: lane&3 = batch-sub, reg = gate
            float g4[4], tmp[4];
#pragma unroll
            for (int v = 0; v < 4; v++) g4[v] = ae[v] + ao[v];
#pragma unroll
            for (int v = 0; v < 4; v++) tmp[v] = __shfl_xor(g4[v ^ 1], 1, 64);
#pragma unroll
            for (int v = 0; v < 4; v++) if ((v & 1) != (lane & 1)) g4[v] = tmp[v];
#pragma unroll
            for (int v = 0; v < 4; v++) tmp[v] = __shfl_xor(g4[v ^ 2], 2, 64);
#pragma unroll
            for (int v = 0; v < 4; v++) if ((v & 2) != (lane & 2)) g4[v] = tmp[v];

            gi = g4[0] + bf2f(xq.x);
            gf = g4[1] + bf2f(xq.y);
            gg = g4[2] + bf2f(xq.z);
            go = g4[3] + bf2f(xq.w);
        }

        // prefetch next step's xg quad (consumed next iteration)
        ushort4 xq_next = xq;
        if (t < 1023)
            xq_next = *(const ushort4*)(xg_lane + (size_t)(t + 1) * 32 * 4096);

        // activation + state (PyTorch order i,f,g,o)
        float iv = sigm(gi);
        float fv = sigm(gf);
        float gv = tanh_fast(gg);
        float ov = sigm(go);
        c = fv * c + iv * gv;
        float h = ov * tanh_fast(c);

        // publish h: pack units (u, u+1) of same batch (lanes L, L+4) into a dword,
        // agent-scope atomic store (write-through to coherent point)
        {
            u32 mine = (u32)f2bf(h);
            u32 other = (u32)__shfl_xor((int)mine, 4, 64);
            if (((lane >> 2) & 1) == 0) {   // even local unit
                u32 packed = mine | (other << 16);
                u32* p = (u32*)&hs[((size_t)(m_lane << 10) + t) * 1024 + u0 + u_lane];
                __hip_atomic_store(p, packed, __ATOMIC_RELAXED, __HIP_MEMORY_SCOPE_AGENT);
            }
        }
        __syncthreads();   // per-wave vmcnt(0) before barrier -> h stores complete
        if (t < 1023 && tid == 0)
            __hip_atomic_store(&flags[bid * 16], (u32)(t + 1),
                               __ATOMIC_RELAXED, __HIP_MEMORY_SCOPE_AGENT);
        xq = xq_next;
    }
}

// ---------------------------------------------------------------- launch
extern "C" void kernel_launch(void* const* d_in, const int* in_sizes, int n_in,
                              void* d_out, int out_size, void* d_ws, size_t ws_size,
                              hipStream_t stream) {
    const float* x     = (const float*)d_in[0];
    const float* W_ih  = (const float*)d_in[1];
    const float* W_hh  = (const float*)d_in[2];
    const float* b_ih  = (const float*)d_in[3];
    const float* b_hh  = (const float*)d_in[4];
    const float* W_key = (const float*)d_in[5];
    const float* b_key = (const float*)d_in[6];
    const float* W_val = (const float*)d_in[7];
    const float* b_val = (const float*)d_in[8];
    float* out = (float*)d_out;

    char* ws = (char*)d_ws;
    u16* xg    = (u16*)(ws);                        // 256 MB  [S*32][4096]
    u16* hs    = (u16*)(ws + 268435456ull);         //  64 MB  [32*1024][1024]
    u16* xb    = (u16*)(ws + 335544320ull);         //  32 MB  x bf16
    u16* whh   = (u16*)(ws + 369098752ull);         //   8 MB
    u16* wih   = (u16*)(ws + 377487360ull);         //   4 MB
    u16* wkv   = (u16*)(ws + 381681664ull);         //   2 MB  [Wkey;Wval]
    u32* flags = (u32*)(ws + 383778816ull);         //   8 KB  barrier flags

    cast_bf16_kernel<<<1024, 256, 0, stream>>>(x, xb, 32 * 1024 * 512);
    cast_bf16_kernel<<<256, 256, 0, stream>>>(W_ih, wih, 4096 * 512);
    cast_bf16_kernel<<<256, 256, 0, stream>>>(W_hh, whh, 4096 * 1024);
    cast_bf16_kernel<<<64, 256, 0, stream>>>(W_key, wkv, 512 * 1024);
    cast_bf16_kernel<<<64, 256, 0, stream>>>(W_val, wkv + 512 * 1024, 512 * 1024);
    init_flags_kernel<<<8, 256, 0, stream>>>(flags);

    // phase 1: xg = x @ W_ih^T + b_ih + b_hh  (row+col permuted bf16)
    gemm_tn<<<dim3(4096 / BN, 32768 / BM), 256, 0, stream>>>(
        xb, wih, 32768, 4096, 512, b_ih, b_hh, xg, nullptr, 1);

    // phase 2: recurrence (cooperative launch for co-residency guarantee)
    {
        void* args[] = { (void*)&whh, (void*)&xg, (void*)&hs, (void*)&flags };
        hipLaunchCooperativeKernel((void*)lstm_rec, dim3(128), dim3(256), args, 0, stream);
    }

    // phase 3: keys/values = hs @ [Wkey;Wval]^T + bias
    gemm_tn<<<dim3(1024 / BN, 32768 / BM), 256, 0, stream>>>(
        hs, wkv, 32768, 1024, 1024, b_key, b_val, nullptr, out, 2);
}